// Round 2
// baseline (2042.862 us; speedup 1.0000x reference)
//
#include <hip/hip_runtime.h>
#include <stdint.h>

#define B_SZ   8192
#define IN_DIM 512
#define HID    256
#define PROJ   128

typedef __attribute__((ext_vector_type(8))) short bf16x8;
typedef __attribute__((ext_vector_type(4))) float f32x4;

__device__ __forceinline__ unsigned short f2bf(float f) {
    union { float f; uint32_t u; } c; c.f = f;
    uint32_t u = c.u;
    uint32_t r = (u + 0x7fffu + ((u >> 16) & 1u)) >> 16;   // RNE
    return (unsigned short)r;
}

// ---------------- K0: convert W2, fused_text, W1 to bf16 ----------------
__global__ __launch_bounds__(256) void k0_convert(
        const float4* __restrict__ W2, const float4* __restrict__ ft,
        const float4* __restrict__ W1,
        ushort4* __restrict__ W2b, ushort4* __restrict__ ftb,
        ushort4* __restrict__ W1b) {
    const int nW2 = (PROJ * IN_DIM * HID) / 4;   // 4,194,304
    const int nft = (B_SZ * IN_DIM) / 4;         // 1,048,576
    const int nW1 = (HID * IN_DIM) / 4;          // 32,768
    const int total = nW2 + nft + nW1;
    int stride = gridDim.x * blockDim.x;
    for (int i = blockIdx.x * blockDim.x + threadIdx.x; i < total; i += stride) {
        const float4* s; ushort4* d; int j;
        if (i < nW2)            { s = W2; d = W2b; j = i; }
        else if (i < nW2 + nft) { s = ft; d = ftb; j = i - nW2; }
        else                    { s = W1; d = W1b; j = i - nW2 - nft; }
        float4 v = s[j];
        ushort4 o;
        o.x = f2bf(v.x); o.y = f2bf(v.y); o.z = f2bf(v.z); o.w = f2bf(v.w);
        d[j] = o;
    }
}

// ---------------- K_XT: transpose x [8192][512] -> xT [512][8192] fp32 ----
__global__ __launch_bounds__(256) void k_xt(
        const float* __restrict__ x, float* __restrict__ xT) {
    __shared__ float tile[64][65];
    const int bi = blockIdx.x & 7;     // i-tile (512/64)
    const int bb = blockIdx.x >> 3;    // b-tile (8192/64)
    const int i0 = bi * 64, b0 = bb * 64;
    const int t = threadIdx.x;
    const int c = t & 63, r4 = t >> 6;
    #pragma unroll
    for (int rr = 0; rr < 64; rr += 4)
        tile[rr + r4][c] = x[(size_t)(b0 + rr + r4) * IN_DIM + i0 + c];
    __syncthreads();
    #pragma unroll
    for (int rr = 0; rr < 64; rr += 4)
        xT[(size_t)(i0 + rr + r4) * B_SZ + b0 + c] = tile[c][rr + r4];
}

// ---------------- K2: out0[b,p] = sum_i x[b,i]*b2[p*512+i]  (fp32) -------
// block: 16 b-rows x 128 p. x tile in LDS (32KB), b2 row L1-resident/thread.
__global__ __launch_bounds__(256) void k2_out0(
        const float* __restrict__ x, const float* __restrict__ b2,
        float* __restrict__ out0) {
    __shared__ float xs[16][IN_DIM];   // 32 KB
    const int t = threadIdx.x;
    const int b0 = blockIdx.x * 16;
    const float4* xsrc = (const float4*)(x + (size_t)b0 * IN_DIM);
    float4* xd = (float4*)&xs[0][0];
    for (int j = t; j < 16 * IN_DIM / 4; j += 256) xd[j] = xsrc[j];
    __syncthreads();
    const int p = t & 127;
    const int bh = t >> 7;             // 0..1
    const float4* br = (const float4*)(b2 + (size_t)p * IN_DIM);
    #pragma unroll 1
    for (int bb = 0; bb < 8; ++bb) {
        const int b = bh * 8 + bb;
        const float4* xr = (const float4*)&xs[b][0];
        float acc = 0.f;
        #pragma unroll 4
        for (int i4 = 0; i4 < IN_DIM / 4; ++i4) {
            float4 xv = xr[i4]; float4 bv = br[i4];
            acc += xv.x * bv.x + xv.y * bv.y + xv.z * bv.z + xv.w * bv.w;
        }
        out0[(size_t)(b0 + b) * PROJ + p] = acc;
    }
}

// ---------------- K1: h = relu(ft @ W1^T + b1), bf16 out ----------------
__global__ __launch_bounds__(256) void k1_hidden(
        const unsigned short* __restrict__ ftb,
        const unsigned short* __restrict__ W1b,
        const float* __restrict__ b1,
        unsigned short* __restrict__ hb) {
    const int lane = threadIdx.x & 63;
    const int wv   = threadIdx.x >> 6;
    const int l15  = lane & 15, q = lane >> 4;
    const int b0 = blockIdx.x * 64;
    const int n0 = wv * 64;

    f32x4 acc[4][4];
    const f32x4 z4 = {0.f, 0.f, 0.f, 0.f};
    #pragma unroll
    for (int mt = 0; mt < 4; ++mt)
        #pragma unroll
        for (int nt = 0; nt < 4; ++nt) acc[mt][nt] = z4;

    for (int kq = 0; kq < 16; ++kq) {
        const int koff = kq * 32 + q * 8;
        bf16x8 a[4], bb[4];
        #pragma unroll
        for (int mt = 0; mt < 4; ++mt)
            a[mt] = *(const bf16x8*)(ftb + (size_t)(b0 + mt*16 + l15) * IN_DIM + koff);
        #pragma unroll
        for (int nt = 0; nt < 4; ++nt)
            bb[nt] = *(const bf16x8*)(W1b + (size_t)(n0 + nt*16 + l15) * IN_DIM + koff);
        #pragma unroll
        for (int mt = 0; mt < 4; ++mt)
            #pragma unroll
            for (int nt = 0; nt < 4; ++nt)
                acc[mt][nt] = __builtin_amdgcn_mfma_f32_16x16x32_bf16(
                    a[mt], bb[nt], acc[mt][nt], 0, 0, 0);
    }
    #pragma unroll
    for (int nt = 0; nt < 4; ++nt) {
        float bias = b1[n0 + nt*16 + l15];
        #pragma unroll
        for (int mt = 0; mt < 4; ++mt)
            #pragma unroll
            for (int r = 0; r < 4; ++r) {
                float v = acc[mt][nt][r] + bias;
                v = fmaxf(v, 0.f);
                hb[(size_t)(b0 + mt*16 + q*4 + r) * HID + n0 + nt*16 + l15] = f2bf(v);
            }
    }
}

// ---------------- K3: out[b,p] = sum_i x*(sum_k h*W2) + out0 -------------
// wave: 64 samples x 4 p's. A (h) register-resident per kh; B (W2 native
// rows) double-buffered at prefetch distance ~2; x via transposed xT with
// dwordx4 loads; b2 folded into out0. No LDS, no barriers.
__global__ __launch_bounds__(256, 3) void k3_main(
        const unsigned short* __restrict__ W2b,
        const unsigned short* __restrict__ hb,
        const float* __restrict__ xT,
        const float* __restrict__ out0,
        float* __restrict__ out) {
    const int lane = threadIdx.x & 63;
    const int wv   = threadIdx.x >> 6;
    const int l15  = lane & 15, q = lane >> 4;
    const int wid  = blockIdx.x * 4 + wv;      // consecutive waves share p-group
    const int b0   = (wid & 127) * 64;
    const int p0   = (wid >> 7) * 4;
    const f32x4 z4 = {0.f, 0.f, 0.f, 0.f};

    #pragma unroll 1
    for (int pp = 0; pp < 4; ++pp) {
        const int p = p0 + pp;
        float oacc[4][4];
        #pragma unroll
        for (int mt = 0; mt < 4; ++mt)
            #pragma unroll
            for (int r = 0; r < 4; ++r) oacc[mt][r] = 0.f;

        #pragma unroll 1
        for (int kh = 0; kh < 2; ++kh) {
            // A-frags: h[b0.., kh*128 .. +128) — 64 VGPRs, reused all 32 steps
            bf16x8 afr[4][4];
            #pragma unroll
            for (int mt = 0; mt < 4; ++mt) {
                const unsigned short* hrow =
                    hb + (size_t)(b0 + mt*16 + l15) * HID + kh*128 + q*8;
                #pragma unroll
                for (int kq = 0; kq < 4; ++kq)
                    afr[mt][kq] = *(const bf16x8*)(hrow + kq*32);
            }
            const unsigned short* wb =
                W2b + ((size_t)p * 512 + l15) * HID + kh*128 + q*8;
            const float* xb = xT + (size_t)l15 * B_SZ + b0 + q*4;

            const unsigned short* wpe = wb;                 // even steps
            const unsigned short* wpo = wb + 16*HID;        // odd steps
            const float* xpe = xb;
            const float* xpo = xb + (size_t)16 * B_SZ;

            bf16x8 bufA[4], bufB[4];
            #pragma unroll
            for (int kq = 0; kq < 4; ++kq) bufA[kq] = *(const bf16x8*)(wpe + kq*32);
            #pragma unroll
            for (int kq = 0; kq < 4; ++kq) bufB[kq] = *(const bf16x8*)(wpo + kq*32);

            #pragma unroll 1
            for (int it2 = 0; it2 < 16; ++it2) {
                // ---- even step (uses bufA) ----
                {
                    f32x4 xv[4];
                    #pragma unroll
                    for (int mt = 0; mt < 4; ++mt)
                        xv[mt] = *(const f32x4*)(xpe + mt*16);
                    f32x4 D[4];
                    #pragma unroll
                    for (int mt = 0; mt < 4; ++mt)
                        D[mt] = __builtin_amdgcn_mfma_f32_16x16x32_bf16(afr[mt][0], bufA[0], z4, 0, 0, 0);
                    #pragma unroll
                    for (int kq = 1; kq < 4; ++kq)
                        #pragma unroll
                        for (int mt = 0; mt < 4; ++mt)
                            D[mt] = __builtin_amdgcn_mfma_f32_16x16x32_bf16(afr[mt][kq], bufA[kq], D[mt], 0, 0, 0);
                    if (it2 < 15) {            // prefetch step it+2 into bufA
                        wpe += 32*HID;
                        #pragma unroll
                        for (int kq = 0; kq < 4; ++kq)
                            bufA[kq] = *(const bf16x8*)(wpe + kq*32);
                    }
                    #pragma unroll
                    for (int mt = 0; mt < 4; ++mt)
                        #pragma unroll
                        for (int r = 0; r < 4; ++r)
                            oacc[mt][r] = fmaf(D[mt][r], xv[mt][r], oacc[mt][r]);
                    xpe += (size_t)32 * B_SZ;
                }
                // ---- odd step (uses bufB) ----
                {
                    f32x4 xv[4];
                    #pragma unroll
                    for (int mt = 0; mt < 4; ++mt)
                        xv[mt] = *(const f32x4*)(xpo + mt*16);
                    f32x4 D[4];
                    #pragma unroll
                    for (int mt = 0; mt < 4; ++mt)
                        D[mt] = __builtin_amdgcn_mfma_f32_16x16x32_bf16(afr[mt][0], bufB[0], z4, 0, 0, 0);
                    #pragma unroll
                    for (int kq = 1; kq < 4; ++kq)
                        #pragma unroll
                        for (int mt = 0; mt < 4; ++mt)
                            D[mt] = __builtin_amdgcn_mfma_f32_16x16x32_bf16(afr[mt][kq], bufB[kq], D[mt], 0, 0, 0);
                    if (it2 < 15) {            // prefetch step it+2 into bufB
                        wpo += 32*HID;
                        #pragma unroll
                        for (int kq = 0; kq < 4; ++kq)
                            bufB[kq] = *(const bf16x8*)(wpo + kq*32);
                    }
                    #pragma unroll
                    for (int mt = 0; mt < 4; ++mt)
                        #pragma unroll
                        for (int r = 0; r < 4; ++r)
                            oacc[mt][r] = fmaf(D[mt][r], xv[mt][r], oacc[mt][r]);
                    xpo += (size_t)32 * B_SZ;
                }
            }
        }
        // reduce over the 16 i-lanes; lane 0 adds out0 and stores
        #pragma unroll
        for (int mt = 0; mt < 4; ++mt)
            #pragma unroll
            for (int r = 0; r < 4; ++r) {
                float v = oacc[mt][r];
                v += __shfl_xor(v, 1, 16);
                v += __shfl_xor(v, 2, 16);
                v += __shfl_xor(v, 4, 16);
                v += __shfl_xor(v, 8, 16);
                if (l15 == 0) {
                    const size_t b = (size_t)(b0 + mt*16 + q*4 + r);
                    out[b * PROJ + p] = v + out0[b * PROJ + p];
                }
            }
    }
}

extern "C" void kernel_launch(void* const* d_in, const int* in_sizes, int n_in,
                              void* d_out, int out_size, void* d_ws, size_t ws_size,
                              hipStream_t stream) {
    const float* ft = (const float*)d_in[0];
    const float* x  = (const float*)d_in[1];
    const float* W1 = (const float*)d_in[2];
    const float* b1 = (const float*)d_in[3];
    const float* W2 = (const float*)d_in[4];
    const float* b2 = (const float*)d_in[5];
    float* out = (float*)d_out;

    char* ws = (char*)d_ws;
    unsigned short* W2b  = (unsigned short*)(ws);             // 33,554,432 B
    unsigned short* ftb  = (unsigned short*)(ws + 33554432);  //  8,388,608 B
    unsigned short* W1b  = (unsigned short*)(ws + 41943040);  //    262,144 B
    unsigned short* hb   = (unsigned short*)(ws + 42205184);  //  4,194,304 B
    float*          xT   = (float*)        (ws + 46399488);   // 16,777,216 B
    float*          out0 = (float*)        (ws + 63176704);   //  4,194,304 B
                                                              // total ~67.4 MB

    hipLaunchKernelGGL(k0_convert, dim3(2048), dim3(256), 0, stream,
        (const float4*)W2, (const float4*)ft, (const float4*)W1,
        (ushort4*)W2b, (ushort4*)ftb, (ushort4*)W1b);
    hipLaunchKernelGGL(k_xt, dim3(1024), dim3(256), 0, stream, x, xT);
    hipLaunchKernelGGL(k2_out0, dim3(512), dim3(256), 0, stream, x, b2, out0);
    hipLaunchKernelGGL(k1_hidden, dim3(128), dim3(256), 0, stream, ftb, W1b, b1, hb);
    hipLaunchKernelGGL(k3_main, dim3(1024), dim3(256), 0, stream, W2b, hb, xT, out0, out);
}

// Round 3
// 783.730 us; speedup vs baseline: 2.6066x; 2.6066x over previous
//
#include <hip/hip_runtime.h>
#include <stdint.h>

#define B_SZ   8192
#define IN_DIM 512
#define HID    256
#define PROJ   128

typedef __attribute__((ext_vector_type(8))) short bf16x8;
typedef __attribute__((ext_vector_type(4))) float f32x4;

#define GLDS16(gp, lp) __builtin_amdgcn_global_load_lds( \
    (const __attribute__((address_space(1))) void*)(gp), \
    (__attribute__((address_space(3))) void*)(lp), 16, 0, 0)

__device__ __forceinline__ unsigned short f2bf(float f) {
    union { float f; uint32_t u; } c; c.f = f;
    uint32_t u = c.u;
    uint32_t r = (u + 0x7fffu + ((u >> 16) & 1u)) >> 16;   // RNE
    return (unsigned short)r;
}

// ---------------- K0: convert W2, fused_text, W1 to bf16 ----------------
__global__ __launch_bounds__(256) void k0_convert(
        const float4* __restrict__ W2, const float4* __restrict__ ft,
        const float4* __restrict__ W1,
        ushort4* __restrict__ W2b, ushort4* __restrict__ ftb,
        ushort4* __restrict__ W1b) {
    const int nW2 = (PROJ * IN_DIM * HID) / 4;
    const int nft = (B_SZ * IN_DIM) / 4;
    const int nW1 = (HID * IN_DIM) / 4;
    const int total = nW2 + nft + nW1;
    int stride = gridDim.x * blockDim.x;
    for (int i = blockIdx.x * blockDim.x + threadIdx.x; i < total; i += stride) {
        const float4* s; ushort4* d; int j;
        if (i < nW2)            { s = W2; d = W2b; j = i; }
        else if (i < nW2 + nft) { s = ft; d = ftb; j = i - nW2; }
        else                    { s = W1; d = W1b; j = i - nW2 - nft; }
        float4 v = s[j];
        ushort4 o;
        o.x = f2bf(v.x); o.y = f2bf(v.y); o.z = f2bf(v.z); o.w = f2bf(v.w);
        d[j] = o;
    }
}

// ---------------- K_XT: transpose x [8192][512] -> xT [512][8192] fp32 ----
__global__ __launch_bounds__(256) void k_xt(
        const float* __restrict__ x, float* __restrict__ xT) {
    __shared__ float tile[64][65];
    const int bi = blockIdx.x & 7;
    const int bb = blockIdx.x >> 3;
    const int i0 = bi * 64, b0 = bb * 64;
    const int t = threadIdx.x;
    const int c = t & 63, r4 = t >> 6;
    #pragma unroll
    for (int rr = 0; rr < 64; rr += 4)
        tile[rr + r4][c] = x[(size_t)(b0 + rr + r4) * IN_DIM + i0 + c];
    __syncthreads();
    #pragma unroll
    for (int rr = 0; rr < 64; rr += 4)
        xT[(size_t)(i0 + rr + r4) * B_SZ + b0 + c] = tile[c][rr + r4];
}

// ---------------- K2: out0[b,p] = sum_i x[b,i]*b2[p*512+i]  (fp32) -------
__global__ __launch_bounds__(256) void k2_out0(
        const float* __restrict__ x, const float* __restrict__ b2,
        float* __restrict__ out0) {
    __shared__ float xs[16][IN_DIM];   // 32 KB
    const int t = threadIdx.x;
    const int b0 = blockIdx.x * 16;
    const float4* xsrc = (const float4*)(x + (size_t)b0 * IN_DIM);
    float4* xd = (float4*)&xs[0][0];
    for (int j = t; j < 16 * IN_DIM / 4; j += 256) xd[j] = xsrc[j];
    __syncthreads();
    const int p = t & 127;
    const int bh = t >> 7;
    const float4* br = (const float4*)(b2 + (size_t)p * IN_DIM);
    #pragma unroll 1
    for (int bb = 0; bb < 8; ++bb) {
        const int b = bh * 8 + bb;
        const float4* xr = (const float4*)&xs[b][0];
        float acc = 0.f;
        #pragma unroll 4
        for (int i4 = 0; i4 < IN_DIM / 4; ++i4) {
            float4 xv = xr[i4]; float4 bv = br[i4];
            acc += xv.x * bv.x + xv.y * bv.y + xv.z * bv.z + xv.w * bv.w;
        }
        out0[(size_t)(b0 + b) * PROJ + p] = acc;
    }
}

// ---------------- K1: h = relu(ft @ W1^T + b1), bf16 out ----------------
__global__ __launch_bounds__(256) void k1_hidden(
        const unsigned short* __restrict__ ftb,
        const unsigned short* __restrict__ W1b,
        const float* __restrict__ b1,
        unsigned short* __restrict__ hb) {
    const int lane = threadIdx.x & 63;
    const int wv   = threadIdx.x >> 6;
    const int l15  = lane & 15, q = lane >> 4;
    const int b0 = blockIdx.x * 64;
    const int n0 = wv * 64;

    f32x4 acc[4][4];
    const f32x4 z4 = {0.f, 0.f, 0.f, 0.f};
    #pragma unroll
    for (int mt = 0; mt < 4; ++mt)
        #pragma unroll
        for (int nt = 0; nt < 4; ++nt) acc[mt][nt] = z4;

    for (int kq = 0; kq < 16; ++kq) {
        const int koff = kq * 32 + q * 8;
        bf16x8 a[4], bb[4];
        #pragma unroll
        for (int mt = 0; mt < 4; ++mt)
            a[mt] = *(const bf16x8*)(ftb + (size_t)(b0 + mt*16 + l15) * IN_DIM + koff);
        #pragma unroll
        for (int nt = 0; nt < 4; ++nt)
            bb[nt] = *(const bf16x8*)(W1b + (size_t)(n0 + nt*16 + l15) * IN_DIM + koff);
        #pragma unroll
        for (int mt = 0; mt < 4; ++mt)
            #pragma unroll
            for (int nt = 0; nt < 4; ++nt)
                acc[mt][nt] = __builtin_amdgcn_mfma_f32_16x16x32_bf16(
                    a[mt], bb[nt], acc[mt][nt], 0, 0, 0);
    }
    #pragma unroll
    for (int nt = 0; nt < 4; ++nt) {
        float bias = b1[n0 + nt*16 + l15];
        #pragma unroll
        for (int mt = 0; mt < 4; ++mt)
            #pragma unroll
            for (int r = 0; r < 4; ++r) {
                float v = acc[mt][nt][r] + bias;
                v = fmaxf(v, 0.f);
                hb[(size_t)(b0 + mt*16 + q*4 + r) * HID + n0 + nt*16 + l15] = f2bf(v);
            }
    }
}

// ---------------- K3: out[b,p] = sum_i x*(sum_k h*W2) + out0 -------------
// Block = 4 waves x 64 b-rows = 256 rows, all sharing one p-pair.
// W2 tiles (2p x 32i x 128k bf16 = 16 KB) double-buffered in LDS via
// global_load_lds width-16, shared by all 4 waves (4x traffic cut).
// Tile loop: t = kh*16 + itile (32 tiles). Prefetch t+1 issued AFTER the
// ready-barrier so its vmcnt drain lands at the end-of-step barrier,
// hidden behind 64 MFMAs. h frags register-resident per kh; x via xT
// dwordx4; b2 folded into out0.
__global__ __launch_bounds__(256, 2) void k3_main(
        const unsigned short* __restrict__ W2b,
        const unsigned short* __restrict__ hb,
        const float* __restrict__ xT,
        const float* __restrict__ out0,
        float* __restrict__ out) {
    __shared__ unsigned short lbs[2][64 * 128];   // 2 x 16 KB
    const int tid  = threadIdx.x;
    const int lane = tid & 63;
    const int wv   = tid >> 6;
    const int l15  = lane & 15, q = lane >> 4;
    const int pgrp = blockIdx.x & 63;             // stride-64 => same XCD for same p
    const int bsup = blockIdx.x >> 6;
    const int p0   = pgrp * 2;
    const int b0w  = bsup * 256 + wv * 64;
    const f32x4 z4 = {0.f, 0.f, 0.f, 0.f};

    // per-thread glds source geometry: 4 instrs, j = wv*4+jj covers tile rows 4j..4j+3
    const int grow_sub = lane >> 4;               // row within 4-row group
    const int gcol     = (lane & 15) * 8;         // k-offset (shorts)

    float oacc[2][4][4];
    #pragma unroll
    for (int pp = 0; pp < 2; ++pp)
        #pragma unroll
        for (int mt = 0; mt < 4; ++mt)
            #pragma unroll
            for (int r = 0; r < 4; ++r) oacc[pp][mt][r] = 0.f;

    bf16x8 afr[4][4];

    // ---- prologue: issue tile 0 ----
    {
        const int kh = 0, i0 = 0;
        #pragma unroll
        for (int jj = 0; jj < 4; ++jj) {
            const int j   = wv * 4 + jj;
            const int row = j * 4 + grow_sub;     // 0..63
            const int p   = row >> 5, ir = row & 31;
            const unsigned short* g = W2b
                + ((size_t)(p0 + p) * IN_DIM + i0 + ir) * HID + kh * 128 + gcol;
            GLDS16(g, &lbs[0][j * 512]);
        }
    }

    #pragma unroll 1
    for (int t = 0; t < 32; ++t) {
        __syncthreads();   // tile t ready (its loads drained at prev end-barrier / here)

        if (t < 31) {      // issue tile t+1; drains at THIS step's end barrier
            const int tn = t + 1;
            const int kh = tn >> 4, i0 = (tn & 15) * 32;
            unsigned short* Ld = lbs[tn & 1];
            #pragma unroll
            for (int jj = 0; jj < 4; ++jj) {
                const int j   = wv * 4 + jj;
                const int row = j * 4 + grow_sub;
                const int p   = row >> 5, ir = row & 31;
                const unsigned short* g = W2b
                    + ((size_t)(p0 + p) * IN_DIM + i0 + ir) * HID + kh * 128 + gcol;
                GLDS16(g, &Ld[j * 512]);
            }
        }

        if ((t & 15) == 0) {   // (re)load h fragments for this K-half
            const int kh = t >> 4;
            #pragma unroll
            for (int mt = 0; mt < 4; ++mt) {
                const unsigned short* hrow =
                    hb + (size_t)(b0w + mt*16 + l15) * HID + kh * 128 + q * 8;
                #pragma unroll
                for (int kq = 0; kq < 4; ++kq)
                    afr[mt][kq] = *(const bf16x8*)(hrow + kq * 32);
            }
        }

        const unsigned short* Lb = lbs[t & 1];
        const int i0 = (t & 15) * 32;

        #pragma unroll
        for (int sub = 0; sub < 2; ++sub) {
            f32x4 xv[4];
            const float* xp = xT + (size_t)(i0 + sub*16 + l15) * B_SZ + b0w + q*4;
            #pragma unroll
            for (int mt = 0; mt < 4; ++mt)
                xv[mt] = *(const f32x4*)(xp + mt * 16);

            #pragma unroll
            for (int pp = 0; pp < 2; ++pp) {
                const unsigned short* Bp = Lb + (pp*32 + sub*16 + l15) * 128 + q*8;
                bf16x8 bfr[4];
                #pragma unroll
                for (int kq = 0; kq < 4; ++kq)
                    bfr[kq] = *(const bf16x8*)(Bp + kq * 32);

                f32x4 D[4];
                #pragma unroll
                for (int mt = 0; mt < 4; ++mt)
                    D[mt] = __builtin_amdgcn_mfma_f32_16x16x32_bf16(afr[mt][0], bfr[0], z4, 0, 0, 0);
                #pragma unroll
                for (int kq = 1; kq < 4; ++kq)
                    #pragma unroll
                    for (int mt = 0; mt < 4; ++mt)
                        D[mt] = __builtin_amdgcn_mfma_f32_16x16x32_bf16(afr[mt][kq], bfr[kq], D[mt], 0, 0, 0);

                #pragma unroll
                for (int mt = 0; mt < 4; ++mt)
                    #pragma unroll
                    for (int r = 0; r < 4; ++r)
                        oacc[pp][mt][r] = fmaf(D[mt][r], xv[mt][r], oacc[pp][mt][r]);
            }
        }

        __syncthreads();   // all waves done reading buf[t&1]; t+1 loads drain here
    }

    // ---- epilogue: reduce over 16 i-lanes, add out0, store ----
    #pragma unroll
    for (int pp = 0; pp < 2; ++pp)
        #pragma unroll
        for (int mt = 0; mt < 4; ++mt)
            #pragma unroll
            for (int r = 0; r < 4; ++r) {
                float v = oacc[pp][mt][r];
                v += __shfl_xor(v, 1, 16);
                v += __shfl_xor(v, 2, 16);
                v += __shfl_xor(v, 4, 16);
                v += __shfl_xor(v, 8, 16);
                if (l15 == 0) {
                    const size_t b = (size_t)(b0w + mt*16 + q*4 + r);
                    out[b * PROJ + p0 + pp] = v + out0[b * PROJ + p0 + pp];
                }
            }
}

extern "C" void kernel_launch(void* const* d_in, const int* in_sizes, int n_in,
                              void* d_out, int out_size, void* d_ws, size_t ws_size,
                              hipStream_t stream) {
    const float* ft = (const float*)d_in[0];
    const float* x  = (const float*)d_in[1];
    const float* W1 = (const float*)d_in[2];
    const float* b1 = (const float*)d_in[3];
    const float* W2 = (const float*)d_in[4];
    const float* b2 = (const float*)d_in[5];
    float* out = (float*)d_out;

    char* ws = (char*)d_ws;
    unsigned short* W2b  = (unsigned short*)(ws);             // 33,554,432 B
    unsigned short* ftb  = (unsigned short*)(ws + 33554432);  //  8,388,608 B
    unsigned short* W1b  = (unsigned short*)(ws + 41943040);  //    262,144 B
    unsigned short* hb   = (unsigned short*)(ws + 42205184);  //  4,194,304 B
    float*          xT   = (float*)        (ws + 46399488);   // 16,777,216 B
    float*          out0 = (float*)        (ws + 63176704);   //  4,194,304 B

    hipLaunchKernelGGL(k0_convert, dim3(2048), dim3(256), 0, stream,
        (const float4*)W2, (const float4*)ft, (const float4*)W1,
        (ushort4*)W2b, (ushort4*)ftb, (ushort4*)W1b);
    hipLaunchKernelGGL(k_xt, dim3(1024), dim3(256), 0, stream, x, xT);
    hipLaunchKernelGGL(k2_out0, dim3(512), dim3(256), 0, stream, x, b2, out0);
    hipLaunchKernelGGL(k1_hidden, dim3(128), dim3(256), 0, stream, ftb, W1b, b1, hb);
    hipLaunchKernelGGL(k3_main, dim3(2048), dim3(256), 0, stream, W2b, hb, xT, out0, out);
}

// Round 4
// 514.364 us; speedup vs baseline: 3.9716x; 1.5237x over previous
//
#include <hip/hip_runtime.h>
#include <stdint.h>

#define B_SZ   8192
#define IN_DIM 512
#define HID    256
#define PROJ   128

typedef __attribute__((ext_vector_type(8))) short bf16x8;
typedef __attribute__((ext_vector_type(4))) float f32x4;

#define GLDS16(gp, lp) __builtin_amdgcn_global_load_lds( \
    (const __attribute__((address_space(1))) void*)(gp), \
    (__attribute__((address_space(3))) void*)(lp), 16, 0, 0)

__device__ __forceinline__ unsigned short f2bf(float f) {
    union { float f; uint32_t u; } c; c.f = f;
    uint32_t u = c.u;
    uint32_t r = (u + 0x7fffu + ((u >> 16) & 1u)) >> 16;   // RNE
    return (unsigned short)r;
}

// ---------------- K0: convert W2, fused_text, W1 to bf16 ----------------
__global__ __launch_bounds__(256) void k0_convert(
        const float4* __restrict__ W2, const float4* __restrict__ ft,
        const float4* __restrict__ W1,
        ushort4* __restrict__ W2b, ushort4* __restrict__ ftb,
        ushort4* __restrict__ W1b) {
    const int nW2 = (PROJ * IN_DIM * HID) / 4;
    const int nft = (B_SZ * IN_DIM) / 4;
    const int nW1 = (HID * IN_DIM) / 4;
    const int total = nW2 + nft + nW1;
    int stride = gridDim.x * blockDim.x;
    for (int i = blockIdx.x * blockDim.x + threadIdx.x; i < total; i += stride) {
        const float4* s; ushort4* d; int j;
        if (i < nW2)            { s = W2; d = W2b; j = i; }
        else if (i < nW2 + nft) { s = ft; d = ftb; j = i - nW2; }
        else                    { s = W1; d = W1b; j = i - nW2 - nft; }
        float4 v = s[j];
        ushort4 o;
        o.x = f2bf(v.x); o.y = f2bf(v.y); o.z = f2bf(v.z); o.w = f2bf(v.w);
        d[j] = o;
    }
}

// ---------------- K_XT: transpose x [8192][512] -> xT [512][8192] fp32 ----
__global__ __launch_bounds__(256) void k_xt(
        const float* __restrict__ x, float* __restrict__ xT) {
    __shared__ float tile[64][65];
    const int bi = blockIdx.x & 7;
    const int bb = blockIdx.x >> 3;
    const int i0 = bi * 64, b0 = bb * 64;
    const int t = threadIdx.x;
    const int c = t & 63, r4 = t >> 6;
    #pragma unroll
    for (int rr = 0; rr < 64; rr += 4)
        tile[rr + r4][c] = x[(size_t)(b0 + rr + r4) * IN_DIM + i0 + c];
    __syncthreads();
    #pragma unroll
    for (int rr = 0; rr < 64; rr += 4)
        xT[(size_t)(i0 + rr + r4) * B_SZ + b0 + c] = tile[c][rr + r4];
}

// ---------------- K2: out0T[p,b] = sum_i x[b,i]*b2[p*512+i]  (fp32) ------
// lanes = b (coalesced xT reads); b2[p,i] is block-uniform -> s_load.
// block: 8 p x 256 b. grid = 16 p-tiles x 32 b-chunks = 512 blocks.
__global__ __launch_bounds__(256) void k2_out0(
        const float* __restrict__ xT, const float* __restrict__ b2,
        float* __restrict__ out0T) {
    const int pt = blockIdx.x >> 5;        // 0..15
    const int bc = blockIdx.x & 31;        // 0..31
    const int b  = bc * 256 + threadIdx.x;
    const int p0 = pt * 8;
    float acc[8];
    #pragma unroll
    for (int pp = 0; pp < 8; ++pp) acc[pp] = 0.f;
    #pragma unroll 4
    for (int i = 0; i < IN_DIM; ++i) {
        float xv = xT[(size_t)i * B_SZ + b];
        #pragma unroll
        for (int pp = 0; pp < 8; ++pp)
            acc[pp] = fmaf(xv, b2[(size_t)(p0 + pp) * IN_DIM + i], acc[pp]);
    }
    #pragma unroll
    for (int pp = 0; pp < 8; ++pp)
        out0T[(size_t)(p0 + pp) * B_SZ + b] = acc[pp];   // coalesced
}

// ---------------- K1: h = relu(ft @ W1^T + b1), bf16 out ----------------
__global__ __launch_bounds__(256) void k1_hidden(
        const unsigned short* __restrict__ ftb,
        const unsigned short* __restrict__ W1b,
        const float* __restrict__ b1,
        unsigned short* __restrict__ hb) {
    const int lane = threadIdx.x & 63;
    const int wv   = threadIdx.x >> 6;
    const int l15  = lane & 15, q = lane >> 4;
    const int b0 = blockIdx.x * 64;
    const int n0 = wv * 64;

    f32x4 acc[4][4];
    const f32x4 z4 = {0.f, 0.f, 0.f, 0.f};
    #pragma unroll
    for (int mt = 0; mt < 4; ++mt)
        #pragma unroll
        for (int nt = 0; nt < 4; ++nt) acc[mt][nt] = z4;

    for (int kq = 0; kq < 16; ++kq) {
        const int koff = kq * 32 + q * 8;
        bf16x8 a[4], bb[4];
        #pragma unroll
        for (int mt = 0; mt < 4; ++mt)
            a[mt] = *(const bf16x8*)(ftb + (size_t)(b0 + mt*16 + l15) * IN_DIM + koff);
        #pragma unroll
        for (int nt = 0; nt < 4; ++nt)
            bb[nt] = *(const bf16x8*)(W1b + (size_t)(n0 + nt*16 + l15) * IN_DIM + koff);
        #pragma unroll
        for (int mt = 0; mt < 4; ++mt)
            #pragma unroll
            for (int nt = 0; nt < 4; ++nt)
                acc[mt][nt] = __builtin_amdgcn_mfma_f32_16x16x32_bf16(
                    a[mt], bb[nt], acc[mt][nt], 0, 0, 0);
    }
    #pragma unroll
    for (int nt = 0; nt < 4; ++nt) {
        float bias = b1[n0 + nt*16 + l15];
        #pragma unroll
        for (int mt = 0; mt < 4; ++mt)
            #pragma unroll
            for (int r = 0; r < 4; ++r) {
                float v = acc[mt][nt][r] + bias;
                v = fmaxf(v, 0.f);
                hb[(size_t)(b0 + mt*16 + q*4 + r) * HID + n0 + nt*16 + l15] = f2bf(v);
            }
    }
}

// ---------------- K3: out[b,p] = sum_i x*(sum_k h*W2) + out0 -------------
// Block = 4 waves x 64 b-rows, sharing one p-pair. W2 tiles (2p x 32i x
// 128k = 16 KB) double-buffered in LDS via global_load_lds width-16.
// LDS layout XOR-swizzled: chunk c (16 B) of row r stored at position
// c ^ (r&7)  ->  B-frag ds_read_b128 is 2-way (free) instead of 16-way.
__global__ __launch_bounds__(256, 3) void k3_main(
        const unsigned short* __restrict__ W2b,
        const unsigned short* __restrict__ hb,
        const float* __restrict__ xT,
        const float* __restrict__ out0T,
        float* __restrict__ out) {
    __shared__ unsigned short lbs[2][64 * 128];   // 2 x 16 KB
    const int tid  = threadIdx.x;
    const int lane = tid & 63;
    const int wv   = tid >> 6;
    const int l15  = lane & 15, q = lane >> 4;
    const int pgrp = blockIdx.x & 63;             // stride-64 => same XCD per p-pair
    const int bsup = blockIdx.x >> 6;
    const int p0   = pgrp * 2;
    const int b0w  = bsup * 256 + wv * 64;
    const f32x4 z4 = {0.f, 0.f, 0.f, 0.f};

    const int grow_sub = lane >> 4;               // row within 4-row group
    const int cbase    = (lane & 15) ^ grow_sub;  // swizzle base for writer

    // reader swizzle constants
    const int qx   = q ^ (l15 & 3);
    const int kbit = (l15 >> 2) & 1;

    float oacc[2][4][4];
    #pragma unroll
    for (int pp = 0; pp < 2; ++pp)
        #pragma unroll
        for (int mt = 0; mt < 4; ++mt)
            #pragma unroll
            for (int r = 0; r < 4; ++r) oacc[pp][mt][r] = 0.f;

    bf16x8 afr[4][4];

    // ---- prologue: issue tile 0 ----
    {
        #pragma unroll
        for (int jj = 0; jj < 4; ++jj) {
            const int j   = wv * 4 + jj;
            const int row = j * 4 + grow_sub;
            const int p   = row >> 5, ir = row & 31;
            const int c   = cbase ^ (4 * (jj & 1));      // source chunk
            const unsigned short* g = W2b
                + ((size_t)(p0 + p) * IN_DIM + ir) * HID + c * 8;
            GLDS16(g, &lbs[0][j * 512]);
        }
    }

    #pragma unroll 1
    for (int t = 0; t < 32; ++t) {
        __syncthreads();   // tile t ready

        if (t < 31) {      // issue tile t+1; drains at this step's end barrier
            const int tn = t + 1;
            const int kh = tn >> 4, i0 = (tn & 15) * 32;
            unsigned short* Ld = lbs[tn & 1];
            #pragma unroll
            for (int jj = 0; jj < 4; ++jj) {
                const int j   = wv * 4 + jj;
                const int row = j * 4 + grow_sub;
                const int p   = row >> 5, ir = row & 31;
                const int c   = cbase ^ (4 * (jj & 1));
                const unsigned short* g = W2b
                    + ((size_t)(p0 + p) * IN_DIM + i0 + ir) * HID + kh * 128 + c * 8;
                GLDS16(g, &Ld[j * 512]);
            }
        }

        if ((t & 15) == 0) {   // (re)load h fragments for this K-half
            const int kh = t >> 4;
            #pragma unroll
            for (int mt = 0; mt < 4; ++mt) {
                const unsigned short* hrow =
                    hb + (size_t)(b0w + mt*16 + l15) * HID + kh * 128 + q * 8;
                #pragma unroll
                for (int kq = 0; kq < 4; ++kq)
                    afr[mt][kq] = *(const bf16x8*)(hrow + kq * 32);
            }
        }

        const unsigned short* Lb = lbs[t & 1];
        const int i0 = (t & 15) * 32;

        #pragma unroll
        for (int sub = 0; sub < 2; ++sub) {
            f32x4 xv[4];
            const float* xp = xT + (size_t)(i0 + sub*16 + l15) * B_SZ + b0w + q*4;
            #pragma unroll
            for (int mt = 0; mt < 4; ++mt)
                xv[mt] = *(const f32x4*)(xp + mt * 16);

            #pragma unroll
            for (int pp = 0; pp < 2; ++pp) {
                const unsigned short* Bp = Lb + (pp*32 + sub*16 + l15) * 128;
                bf16x8 bfr[4];
                #pragma unroll
                for (int kq = 0; kq < 4; ++kq) {
                    const int cpos = qx + 4 * (kq ^ kbit);   // swizzled chunk pos
                    bfr[kq] = *(const bf16x8*)(Bp + cpos * 8);
                }

                f32x4 D[4];
                #pragma unroll
                for (int mt = 0; mt < 4; ++mt)
                    D[mt] = __builtin_amdgcn_mfma_f32_16x16x32_bf16(afr[mt][0], bfr[0], z4, 0, 0, 0);
                #pragma unroll
                for (int kq = 1; kq < 4; ++kq)
                    #pragma unroll
                    for (int mt = 0; mt < 4; ++mt)
                        D[mt] = __builtin_amdgcn_mfma_f32_16x16x32_bf16(afr[mt][kq], bfr[kq], D[mt], 0, 0, 0);

                #pragma unroll
                for (int mt = 0; mt < 4; ++mt)
                    #pragma unroll
                    for (int r = 0; r < 4; ++r)
                        oacc[pp][mt][r] = fmaf(D[mt][r], xv[mt][r], oacc[pp][mt][r]);
            }
        }

        __syncthreads();   // all waves done reading buf[t&1]
    }

    // ---- epilogue: reduce over 16 i-lanes, add out0, store ----
    #pragma unroll
    for (int pp = 0; pp < 2; ++pp)
        #pragma unroll
        for (int mt = 0; mt < 4; ++mt)
            #pragma unroll
            for (int r = 0; r < 4; ++r) {
                float v = oacc[pp][mt][r];
                v += __shfl_xor(v, 1, 16);
                v += __shfl_xor(v, 2, 16);
                v += __shfl_xor(v, 4, 16);
                v += __shfl_xor(v, 8, 16);
                if (l15 == 0) {
                    const size_t b = (size_t)(b0w + mt*16 + q*4 + r);
                    out[b * PROJ + p0 + pp] = v + out0T[(size_t)(p0 + pp) * B_SZ + b];
                }
            }
}

extern "C" void kernel_launch(void* const* d_in, const int* in_sizes, int n_in,
                              void* d_out, int out_size, void* d_ws, size_t ws_size,
                              hipStream_t stream) {
    const float* ft = (const float*)d_in[0];
    const float* x  = (const float*)d_in[1];
    const float* W1 = (const float*)d_in[2];
    const float* b1 = (const float*)d_in[3];
    const float* W2 = (const float*)d_in[4];
    const float* b2 = (const float*)d_in[5];
    float* out = (float*)d_out;

    char* ws = (char*)d_ws;
    unsigned short* W2b   = (unsigned short*)(ws);             // 33,554,432 B
    unsigned short* ftb   = (unsigned short*)(ws + 33554432);  //  8,388,608 B
    unsigned short* W1b   = (unsigned short*)(ws + 41943040);  //    262,144 B
    unsigned short* hb    = (unsigned short*)(ws + 42205184);  //  4,194,304 B
    float*          xT    = (float*)        (ws + 46399488);   // 16,777,216 B
    float*          out0T = (float*)        (ws + 63176704);   //  4,194,304 B

    hipLaunchKernelGGL(k0_convert, dim3(2048), dim3(256), 0, stream,
        (const float4*)W2, (const float4*)ft, (const float4*)W1,
        (ushort4*)W2b, (ushort4*)ftb, (ushort4*)W1b);
    hipLaunchKernelGGL(k_xt, dim3(1024), dim3(256), 0, stream, x, xT);
    hipLaunchKernelGGL(k2_out0, dim3(512), dim3(256), 0, stream, xT, b2, out0T);
    hipLaunchKernelGGL(k1_hidden, dim3(128), dim3(256), 0, stream, ftb, W1b, b1, hb);
    hipLaunchKernelGGL(k3_main, dim3(2048), dim3(256), 0, stream, W2b, hb, xT, out0T, out);
}